// Round 1
// 194.770 us; speedup vs baseline: 1.0265x; 1.0265x over previous
//
#include <hip/hip_runtime.h>
#include <math.h>

// ---- static config (mirrors reference) ----
#define BB 16
#define AA 3
#define NCC 80
#define WW 76
#define MM 32
#define CELLS_PER_IMG (AA * WW * WW)          // 17328
#define NDECODE (BB * CELLS_PER_IMG * 85)     // 23,566,080
#define NCELLS (BB * CELLS_PER_IMG)           // 277,248
#define N4 (NDECODE / 4)                      // 5,891,520 float4s

typedef float vfloat4 __attribute__((ext_vector_type(4)));

__constant__ float c_anchor[9][2] = {
    {10.f,13.f},{16.f,30.f},{33.f,23.f},{30.f,61.f},{62.f,45.f},
    {59.f,119.f},{116.f,90.f},{156.f,198.f},{373.f,326.f}};

#define LOG2E 1.4426950408889634f

__device__ __forceinline__ float fast_sigmoid(float x) {
    return __builtin_amdgcn_rcpf(1.0f + __builtin_amdgcn_exp2f(-x * LOG2E));
}

__device__ __forceinline__ vfloat4 sig4(vfloat4 v) {
    vfloat4 o;
    o.x = fast_sigmoid(v.x);
    o.y = fast_sigmoid(v.y);
    o.z = fast_sigmoid(v.z);
    o.w = fast_sigmoid(v.w);
    return o;
}

// ---------------------------------------------------------------------------
// Slow-path fixup for one float4 chunk. A chunk [b, b+4) intersects at most
// one box window [85*cell, 85*cell+4) (windows are 85 apart). Locate it with
// ONE division; hoist gi/gj/anchor (3 shared div chains instead of up to 8
// per-element chains); anchor*0.125 folded to exact FP constants selected by
// cndmask (no indexed constant-mem load); sigmoid reused, not recomputed.
// Replaces the old ~300-inst nested-divergent block with ~65 inst.
// Semantics identical to the passing kernel:
//   c==0: sig + cell%76      c==1: sig + (cell/76)%76
//   c==2: exp2(x*log2e) * aw*0.125   c==3: ... * ah*0.125
// ---------------------------------------------------------------------------
__device__ __forceinline__ void fix_chunk(unsigned i4, const vfloat4 v, vfloat4& o,
                                          float* __restrict__ boxes) {
    unsigned b = i4 * 4u;
    unsigned cell = (b + 3u) / 85u;           // largest cell with 85*cell <= b+3
    int s = (int)(cell * 85u) - (int)b;       // window start rel. to b, in (-85, 3]
    if (s >= -3) {                            // == (r<4 || r>81) of the old kernel
        unsigned t  = cell / 76u;
        unsigned gi = cell - t * 76u;         // cell % 76
        unsigned t2 = t / 76u;
        unsigned gj = t - t2 * 76u;           // (cell/76) % 76
        unsigned a  = t2 % 3u;                // (cell/5776) % 3
        float aw = (a == 0u) ? 1.25f  : ((a == 1u) ? 2.0f  : 4.125f); // {10,16,33}*0.125
        float ah = (a == 0u) ? 1.625f : ((a == 1u) ? 3.75f : 2.875f); // {13,30,23}*0.125
        float q0 = (float)gi, q1 = (float)gj;
        float raw[4] = {v.x, v.y, v.z, v.w};
        float sg[4]  = {o.x, o.y, o.z, o.w};
        float res[4] = {o.x, o.y, o.z, o.w};
        float* bp = boxes + (size_t)cell * 4u;
#pragma unroll
        for (int j = 0; j < 4; ++j) {         // j compile-time: all regs, no scratch
            int k = j - s;                    // channel index if inside window
            if ((unsigned)k < 4u) {
                float e    = __builtin_amdgcn_exp2f(raw[j] * LOG2E);
                float addq = (k == 0) ? q0 : q1;
                float an   = (k == 2) ? aw : ah;
                float val  = (k < 2) ? (sg[j] + addq) : (e * an);
                res[j] = val;
                bp[k]  = val;
            }
        }
        o.x = res[0]; o.y = res[1]; o.z = res[2]; o.w = res[3];
    }
}

// ---------------------------------------------------------------------------
// Kernel 1: decode. Wave-tiled, 4 float4s per thread:
//   i_k = wave*256 + k*64 + lane  -> unit-stride coalescing per instruction,
// 4 independent loads in flight (addresses clamped so all loads issue before
// any use; bounds predicates are wave-uniform since N4 % 64 == 0).
// Non-temporal stores for dec (write-once output) keep the input resident in
// L3 across iterations. No RMW into dec (R6 lesson); boxes written normally
// (consumed by kernel 2).
// ---------------------------------------------------------------------------
__global__ __launch_bounds__(256) void decode_kernel(const vfloat4* __restrict__ in,
                                                     vfloat4* __restrict__ out,
                                                     float* __restrict__ boxes) {
    unsigned tid  = blockIdx.x * 256u + threadIdx.x;
    unsigned wave = tid >> 6;
    unsigned lane = tid & 63u;
    unsigned i0 = wave * 256u + lane;
    unsigned i1 = i0 + 64u;
    unsigned i2 = i0 + 128u;
    unsigned i3 = i0 + 192u;
    const unsigned last = N4 - 1u;

    // clamped, unconditional loads -> 4 loads in flight, no branch between them
    vfloat4 v0 = in[i0 < last ? i0 : last];
    vfloat4 v1 = in[i1 < last ? i1 : last];
    vfloat4 v2 = in[i2 < last ? i2 : last];
    vfloat4 v3 = in[i3 < last ? i3 : last];

    bool p0 = i0 < N4, p1 = i1 < N4, p2 = i2 < N4, p3 = i3 < N4;  // wave-uniform

    vfloat4 o0 = sig4(v0);
    vfloat4 o1 = sig4(v1);
    vfloat4 o2 = sig4(v2);
    vfloat4 o3 = sig4(v3);

    if (p0) fix_chunk(i0, v0, o0, boxes);
    if (p1) fix_chunk(i1, v1, o1, boxes);
    if (p2) fix_chunk(i2, v2, o2, boxes);
    if (p3) fix_chunk(i3, v3, o3, boxes);

    if (p0) __builtin_nontemporal_store(o0, &out[i0]);
    if (p1) __builtin_nontemporal_store(o1, &out[i1]);
    if (p2) __builtin_nontemporal_store(o2, &out[i2]);
    if (p3) __builtin_nontemporal_store(o3, &out[i3]);
}

// ---------------------------------------------------------------------------
// Kernel 2: per-cell max-IoU vs the image's 32 GT boxes -> noobj; zero obj.
// (unchanged — not in the top dispatches)
// ---------------------------------------------------------------------------
__global__ void noobj_kernel(const float4* __restrict__ boxes, const float* __restrict__ gt,
                             float* __restrict__ noobj, float* __restrict__ obj) {
    __shared__ float4 sbox[MM];
    int b = blockIdx.y;
    int t = threadIdx.x;
    if (t < MM) {
        const float* g = gt + (size_t)(b * MM + t) * 6;
        float cx = g[1], cy = g[2], gw = g[3], gh = g[4];
        sbox[t] = make_float4((cx - gw * 0.5f) * 608.0f, (cy - gh * 0.5f) * 608.0f,
                              (cx + gw * 0.5f) * 608.0f, (cy + gh * 0.5f) * 608.0f);
    }
    __syncthreads();
    int n = blockIdx.x * blockDim.x + t;
    if (n >= CELLS_PER_IMG) return;
    size_t idx = (size_t)b * CELLS_PER_IMG + n;
    float4 pb = boxes[idx];
    float px = pb.x, py = pb.y, pw = pb.z, ph = pb.w;
    float x1 = (px - pw * 0.5f) / 76.0f * 608.0f;
    float y1 = (py - ph * 0.5f) / 76.0f * 608.0f;
    float x2 = (px + pw * 0.5f) / 76.0f * 608.0f;
    float y2 = (py + ph * 0.5f) / 76.0f * 608.0f;
    float area2 = (x2 - x1) * (y2 - y1);
    float best = 0.0f;
#pragma unroll
    for (int m = 0; m < MM; ++m) {
        float4 gb = sbox[m];
        float area1 = (gb.z - gb.x) * (gb.w - gb.y);
        float ltx = fmaxf(gb.x, x1), lty = fmaxf(gb.y, y1);
        float rbx = fminf(gb.z, x2), rby = fminf(gb.w, y2);
        float inter = fmaxf(rbx - ltx, 0.0f) * fmaxf(rby - lty, 0.0f);
        float iou = inter * __builtin_amdgcn_rcpf(area1 + area2 - inter);
        best = fmaxf(best, iou);
    }
    noobj[idx] = (best <= 0.5f) ? 1.0f : 0.0f;
    obj[idx] = 0.0f;
}

// ---------------------------------------------------------------------------
// Kernel 3: per-GT best-anchor argmax. (unchanged)
// ---------------------------------------------------------------------------
__global__ void assign_kernel(const float* __restrict__ gt,
                              float* __restrict__ noobj, float* __restrict__ obj) {
    int r = blockIdx.x * blockDim.x + threadIdx.x;
    if (r >= BB * MM) return;
    const float* g = gt + (size_t)r * 6;
    float cx = g[1], cy = g[2], gw = g[3], gh = g[4];
    float gx1 = (cx - gw * 0.5f) * 608.0f, gy1 = (cy - gh * 0.5f) * 608.0f;
    float gx2 = (cx + gw * 0.5f) * 608.0f, gy2 = (cy + gh * 0.5f) * 608.0f;
    float area_g = (gx2 - gx1) * (gy2 - gy1);
    int best = 0;
    float bestv = -1.0f;
#pragma unroll
    for (int k = 0; k < 9; ++k) {
        float ow = c_anchor[k][0] / 608.0f, oh = c_anchor[k][1] / 608.0f;
        float ax1 = (cx - ow * 0.5f) * 608.0f, ay1 = (cy - oh * 0.5f) * 608.0f;
        float ax2 = (cx + ow * 0.5f) * 608.0f, ay2 = (cy + oh * 0.5f) * 608.0f;
        float ltx = fmaxf(gx1, ax1), lty = fmaxf(gy1, ay1);
        float rbx = fminf(gx2, ax2), rby = fminf(gy2, ay2);
        float inter = fmaxf(rbx - ltx, 0.0f) * fmaxf(rby - lty, 0.0f);
        float area_a = (ax2 - ax1) * (ay2 - ay1);
        float v = inter / (area_g + area_a - inter);
        if (v > bestv) { bestv = v; best = k; }
    }
    if (best < AA) {
        int b = r / MM;
        int gi = (int)(cx * 76.0f);
        int gj = (int)(cy * 76.0f);
        int flat = ((b * AA + best) * WW + gi) * WW + gj;
        obj[flat] = 1.0f;
        noobj[flat] = 0.0f;
    }
}

extern "C" void kernel_launch(void* const* d_in, const int* in_sizes, int n_in,
                              void* d_out, int out_size, void* d_ws, size_t ws_size,
                              hipStream_t stream) {
    const float* pred = (const float*)d_in[0];
    const float* gt   = (const float*)d_in[1];
    float* dec   = (float*)d_out;            // 23,566,080
    float* noobj = dec + NDECODE;            //    277,248
    float* obj   = noobj + NCELLS;           //    277,248
    float* boxes = (float*)d_ws;             // NCELLS*4 floats = 4.4 MB scratch

    // 4 float4s per thread, wave-tiled: one wave covers 256 float4s.
    const int nblocks = (N4 + 1023) / 1024;  // 5754
    decode_kernel<<<nblocks, 256, 0, stream>>>(
        (const vfloat4*)pred, (vfloat4*)dec, boxes);

    dim3 gb((CELLS_PER_IMG + 255) / 256, BB);
    noobj_kernel<<<gb, 256, 0, stream>>>((const float4*)boxes, gt, noobj, obj);

    assign_kernel<<<2, 256, 0, stream>>>(gt, noobj, obj);
}